// Round 1
// baseline (133.581 us; speedup 1.0000x reference)
//
#include <hip/hip_runtime.h>
#include <math.h>

#define NCH    1024          // channels
#define NN     64            // nodes (8x8)
#define CK     32            // channels per staged chunk
#define NCHUNK (NCH / CK)    // 32
#define KSC    28.853900817779268f   // 20 * log2(e)  (exp(-cost/0.05) = 2^((sim-1)*KSC))

// stats accumulation from staged registers
#define STAT_Q(v) { sqp[0]+=(v).x; q2p[0]=fmaf((v).x,(v).x,q2p[0]); \
                    sqp[1]+=(v).y; q2p[1]=fmaf((v).y,(v).y,q2p[1]); \
                    sqp[2]+=(v).z; q2p[2]=fmaf((v).z,(v).z,q2p[2]); \
                    sqp[3]+=(v).w; q2p[3]=fmaf((v).w,(v).w,q2p[3]); }
#define STAT_P(v) { spp[0]+=(v).x; p2p[0]=fmaf((v).x,(v).x,p2p[0]); \
                    spp[1]+=(v).y; p2p[1]=fmaf((v).y,(v).y,p2p[1]); \
                    spp[2]+=(v).z; p2p[2]=fmaf((v).z,(v).z,p2p[2]); \
                    spp[3]+=(v).w; p2p[3]=fmaf((v).w,(v).w,p2p[3]); }

__global__ __launch_bounds__(256)
void deepemd_fused(const float* __restrict__ proto,
                   const float* __restrict__ query,
                   float* __restrict__ out)
{
    // stage: q chunk [CK][64] at 0, p chunk at 2048; reused as reduction scratch later
    __shared__ __align__(16) float stage[2 * CK * NN];      // 16 KB
    __shared__ __align__(16) float Kl [NN][68];             // padded: 17.4 KB
    __shared__ __align__(16) float KTl[NN][68];             // 17.4 KB
    __shared__ __align__(16) float statL[4][NN];            // sq, q2, sp, p2
    __shared__ __align__(16) float uL[NN];
    __shared__ __align__(16) float vL[NN];
    __shared__ __align__(16) float rL[NN];
    __shared__ __align__(16) float cL[NN];
    __shared__ float redl[4];

    const int b  = blockIdx.x;
    const int t  = threadIdx.x;
    const int tr = t >> 4;            // 0..15
    const int tc = t & 15;            // 0..15
    const int n0 = tr * 4;            // query-node rows owned (4)
    const int m0 = tc * 4;            // proto-node cols owned (4)
    const int ofs = 4 * t;            // 0..1020 floats within half-chunk

    const float* __restrict__ pb = proto + (size_t)b * (NCH * NN);
    const float* __restrict__ qb = query + (size_t)b * (NCH * NN);

    float acc[4][4];
    #pragma unroll
    for (int i = 0; i < 4; ++i) {
        #pragma unroll
        for (int j = 0; j < 4; ++j) acc[i][j] = 0.0f;
    }
    float sqp[4] = {0,0,0,0}, q2p[4] = {0,0,0,0};
    float spp[4] = {0,0,0,0}, p2p[4] = {0,0,0,0};

    // ---------- prologue: load chunk 0 into registers ----------
    float4 qv0 = *(const float4*)(qb + ofs);
    float4 qv1 = *(const float4*)(qb + 1024 + ofs);
    float4 pv0 = *(const float4*)(pb + ofs);
    float4 pv1 = *(const float4*)(pb + 1024 + ofs);

    // ---------- streaming Gram + stats ----------
    for (int ch = 0; ch < NCHUNK; ++ch) {
        if (ch) __syncthreads();               // prev chunk's readers done
        *(float4*)&stage[       ofs] = qv0;
        *(float4*)&stage[1024 + ofs] = qv1;
        *(float4*)&stage[2048 + ofs] = pv0;
        *(float4*)&stage[3072 + ofs] = pv1;

        float4 nq0, nq1, np0, np1;
        const bool more = (ch + 1 < NCHUNK);
        if (more) {                            // issue next-chunk loads early (hide HBM latency)
            const float* qn = qb + (ch + 1) * 2048;
            const float* pn = pb + (ch + 1) * 2048;
            nq0 = *(const float4*)(qn + ofs);
            nq1 = *(const float4*)(qn + 1024 + ofs);
            np0 = *(const float4*)(pn + ofs);
            np1 = *(const float4*)(pn + 1024 + ofs);
        }

        // per-node raw sums / sumsq (cols 4*tc..+3, fixed per thread)
        STAT_Q(qv0); STAT_Q(qv1);
        STAT_P(pv0); STAT_P(pv1);

        __syncthreads();                       // staged chunk visible

        #pragma unroll 8
        for (int cc = 0; cc < CK; ++cc) {
            float4 a  = *(const float4*)&stage[cc * 64 + n0];
            float4 bb = *(const float4*)&stage[2048 + cc * 64 + m0];
            acc[0][0]=fmaf(a.x,bb.x,acc[0][0]); acc[0][1]=fmaf(a.x,bb.y,acc[0][1]);
            acc[0][2]=fmaf(a.x,bb.z,acc[0][2]); acc[0][3]=fmaf(a.x,bb.w,acc[0][3]);
            acc[1][0]=fmaf(a.y,bb.x,acc[1][0]); acc[1][1]=fmaf(a.y,bb.y,acc[1][1]);
            acc[1][2]=fmaf(a.y,bb.z,acc[1][2]); acc[1][3]=fmaf(a.y,bb.w,acc[1][3]);
            acc[2][0]=fmaf(a.z,bb.x,acc[2][0]); acc[2][1]=fmaf(a.z,bb.y,acc[2][1]);
            acc[2][2]=fmaf(a.z,bb.z,acc[2][2]); acc[2][3]=fmaf(a.z,bb.w,acc[2][3]);
            acc[3][0]=fmaf(a.w,bb.x,acc[3][0]); acc[3][1]=fmaf(a.w,bb.y,acc[3][1]);
            acc[3][2]=fmaf(a.w,bb.z,acc[3][2]); acc[3][3]=fmaf(a.w,bb.w,acc[3][3]);
        }
        if (more) { qv0 = nq0; qv1 = nq1; pv0 = np0; pv1 = np1; }
    }
    __syncthreads();                           // gram done; stage reusable

    // ---------- row sums of raw Gram (-> weight_1) via shfl within 16-lane groups ----------
    #pragma unroll
    for (int i = 0; i < 4; ++i) {
        float s = acc[i][0] + acc[i][1] + acc[i][2] + acc[i][3];
        s += __shfl_xor(s, 1, 64); s += __shfl_xor(s, 2, 64);
        s += __shfl_xor(s, 4, 64); s += __shfl_xor(s, 8, 64);
        if (tc == 0) uL[n0 + i] = s;           // uL as rowsum temp
    }
    // ---------- dump stats partials ----------
    #pragma unroll
    for (int k = 0; k < 4; ++k) {
        stage[t*16 +      k] = sqp[k];
        stage[t*16 +  4 + k] = q2p[k];
        stage[t*16 +  8 + k] = spp[k];
        stage[t*16 + 12 + k] = p2p[k];
    }
    __syncthreads();

    if (t < NN) {                              // reduce stats: contributors t' = j*16 + (t>>2)
        const int g = t >> 2, k = t & 3;
        float ssq = 0, sq2 = 0, ssp = 0, sp2 = 0;
        #pragma unroll
        for (int j = 0; j < 16; ++j) {
            const float* row = &stage[(j * 16 + g) * 16];
            ssq += row[k]; sq2 += row[4 + k]; ssp += row[8 + k]; sp2 += row[12 + k];
        }
        statL[0][t] = ssq; statL[1][t] = sq2; statL[2][t] = ssp; statL[3][t] = sp2;
    }
    __syncthreads();                           // stats reads done; stage reusable again

    // ---------- col sums of raw Gram (-> weight_2) via LDS ----------
    #pragma unroll
    for (int j = 0; j < 4; ++j) {
        float s = acc[0][j] + acc[1][j] + acc[2][j] + acc[3][j];
        stage[tr * 64 + m0 + j] = s;           // [16][64] partials
    }
    __syncthreads();

    if (t < NN) {
        float cs = 0;
        #pragma unroll
        for (int i = 0; i < 16; ++i) cs += stage[i * 64 + t];
        float w2 = fmaxf(cs * (1.0f/64.0f), 0.0f) + 0.001f;
        float w1 = fmaxf(uL[t] * (1.0f/64.0f), 0.0f) + 0.001f;
        float s1 = w1, s2 = w2;                // threads 0..63 form wave 0
        #pragma unroll
        for (int m = 1; m < 64; m <<= 1) {
            s1 += __shfl_xor(s1, m, 64);
            s2 += __shfl_xor(s2, m, 64);
        }
        rL[t] = w1 / s1;
        cL[t] = w2 / s2;
        vL[t] = 1.0f;
    }
    __syncthreads();

    // ---------- sim (kept in acc regs) + K, K^T into LDS ----------
    float nq_[4], np_[4], sqn[4], spm[4];
    #pragma unroll
    for (int i = 0; i < 4; ++i) {
        float sv = statL[0][n0 + i];
        float var = statL[1][n0 + i] - sv * sv * (1.0f/1024.0f);
        nq_[i] = fmaxf(sqrtf(fmaxf(var, 0.0f)), 1e-8f);
        sqn[i] = sv;
    }
    #pragma unroll
    for (int j = 0; j < 4; ++j) {
        float sv = statL[2][m0 + j];
        float var = statL[3][m0 + j] - sv * sv * (1.0f/1024.0f);
        np_[j] = fmaxf(sqrtf(fmaxf(var, 0.0f)), 1e-8f);
        spm[j] = sv;
    }
    #pragma unroll
    for (int i = 0; i < 4; ++i) {
        #pragma unroll
        for (int j = 0; j < 4; ++j) {
            float sim = (acc[i][j] - sqn[i] * spm[j] * (1.0f/1024.0f)) / (nq_[i] * np_[j]);
            acc[i][j] = sim;                   // keep sim for the final reduction
            float Kv = exp2f((sim - 1.0f) * KSC);
            Kl [n0 + i][m0 + j] = Kv;
            KTl[m0 + j][n0 + i] = Kv;
        }
    }
    __syncthreads();

    // ---------- Sinkhorn: K row-slices in registers, 4 threads per row ----------
    const int sn  = t >> 2;                    // row (u-step) / col (v-step) 0..63
    const int sp4 = t & 3;                     // 16-wide slice id
    float Kr[16], KTr[16];
    #pragma unroll
    for (int jj = 0; jj < 4; ++jj) {
        float4 kv = *(const float4*)&Kl [sn][sp4 * 16 + jj * 4];
        float4 kt = *(const float4*)&KTl[sn][sp4 * 16 + jj * 4];
        Kr [jj*4+0]=kv.x; Kr [jj*4+1]=kv.y; Kr [jj*4+2]=kv.z; Kr [jj*4+3]=kv.w;
        KTr[jj*4+0]=kt.x; KTr[jj*4+1]=kt.y; KTr[jj*4+2]=kt.z; KTr[jj*4+3]=kt.w;
    }
    const float rreg = rL[sn];
    const float creg = cL[sn];

    #define DOT16(KK, ARR) ({ \
        float4 x0 = *(const float4*)&ARR[sp4*16 +  0]; \
        float4 x1 = *(const float4*)&ARR[sp4*16 +  4]; \
        float4 x2 = *(const float4*)&ARR[sp4*16 +  8]; \
        float4 x3 = *(const float4*)&ARR[sp4*16 + 12]; \
        float a0 = 0.0f, a1 = 0.0f; \
        a0=fmaf(KK[0],x0.x,a0);  a1=fmaf(KK[1],x0.y,a1); \
        a0=fmaf(KK[2],x0.z,a0);  a1=fmaf(KK[3],x0.w,a1); \
        a0=fmaf(KK[4],x1.x,a0);  a1=fmaf(KK[5],x1.y,a1); \
        a0=fmaf(KK[6],x1.z,a0);  a1=fmaf(KK[7],x1.w,a1); \
        a0=fmaf(KK[8],x2.x,a0);  a1=fmaf(KK[9],x2.y,a1); \
        a0=fmaf(KK[10],x2.z,a0); a1=fmaf(KK[11],x2.w,a1); \
        a0=fmaf(KK[12],x3.x,a0); a1=fmaf(KK[13],x3.y,a1); \
        a0=fmaf(KK[14],x3.z,a0); a1=fmaf(KK[15],x3.w,a1); \
        a0 + a1; })

    for (int it = 0; it < 100; ++it) {
        // u = r / max(K v, 1e-30)
        float s = DOT16(Kr, vL);
        s += __shfl_xor(s, 1, 64); s += __shfl_xor(s, 2, 64);
        float u = rreg / fmaxf(s, 1e-30f);
        if (sp4 == 0) uL[sn] = u;
        __syncthreads();
        // v = c / max(K^T u, 1e-30)
        float s2 = DOT16(KTr, uL);
        s2 += __shfl_xor(s2, 1, 64); s2 += __shfl_xor(s2, 2, 64);
        float vv = creg / fmaxf(s2, 1e-30f);
        if (sp4 == 0) vL[sn] = vv;
        __syncthreads();
    }
    // final u-step
    {
        float s = DOT16(Kr, vL);
        s += __shfl_xor(s, 1, 64); s += __shfl_xor(s, 2, 64);
        float u = rreg / fmaxf(s, 1e-30f);
        if (sp4 == 0) uL[sn] = u;
    }
    __syncthreads();

    // ---------- logits = sum(sim * u*K*v) * (T / N) ----------
    float uu[4], vv_[4];
    #pragma unroll
    for (int i = 0; i < 4; ++i) uu[i]  = uL[n0 + i];
    #pragma unroll
    for (int j = 0; j < 4; ++j) vv_[j] = vL[m0 + j];
    float part = 0.0f;
    #pragma unroll
    for (int i = 0; i < 4; ++i) {
        #pragma unroll
        for (int j = 0; j < 4; ++j) {
            float sim = acc[i][j];
            float Kv  = exp2f((sim - 1.0f) * KSC);
            part = fmaf(sim * Kv, uu[i] * vv_[j], part);
        }
    }
    #pragma unroll
    for (int m = 1; m < 64; m <<= 1) part += __shfl_xor(part, m, 64);
    if ((t & 63) == 0) redl[t >> 6] = part;
    __syncthreads();
    if (t == 0) out[b] = (redl[0] + redl[1] + redl[2] + redl[3]) * (12.5f / 64.0f);
}

extern "C" void kernel_launch(void* const* d_in, const int* in_sizes, int n_in,
                              void* d_out, int out_size, void* d_ws, size_t ws_size,
                              hipStream_t stream) {
    const float* proto = (const float*)d_in[0];
    const float* query = (const float*)d_in[1];
    float* out = (float*)d_out;
    (void)in_sizes; (void)n_in; (void)d_ws; (void)ws_size; (void)out_size;
    deepemd_fused<<<dim3(512), dim3(256), 0, stream>>>(proto, query, out);
}